// Round 1
// baseline (1543.805 us; speedup 1.0000x reference)
//
#include <hip/hip_runtime.h>
#include <math.h>

#define EPSF 1e-10f

struct WS {
  double sum_mse;
  double sum_ce;
  unsigned int minU[10];
  unsigned int maxU[10];
  unsigned int hist[208]; // [0..99] single, [100..199] married, [200]=cnt_single, [201]=cnt_married
};

__device__ __forceinline__ unsigned f2o(float f){
  unsigned u = __float_as_uint(f);
  return (u & 0x80000000u) ? ~u : (u | 0x80000000u);
}
__device__ __forceinline__ float o2f(unsigned u){
  unsigned v = (u & 0x80000000u) ? (u ^ 0x80000000u) : ~u;
  return __uint_as_float(v);
}

__global__ void k_init(WS* ws){
  int t = threadIdx.x;
  if (t == 0){ ws->sum_mse = 0.0; ws->sum_ce = 0.0; }
  if (t < 10){ ws->minU[t] = 0xFFFFFFFFu; ws->maxU[t] = 0u; }
  for (int i = t; i < 208; i += blockDim.x) ws->hist[i] = 0u;
}

template<int S, int E>
__device__ __forceinline__ float ce_block(const float* d, const float* t){
  float mx = d[S];
  #pragma unroll
  for (int j = S + 1; j < E; j++) mx = fmaxf(mx, d[j]);
  float se = 0.f, dot = 0.f;
  #pragma unroll
  for (int j = S; j < E; j++){ se += __expf(d[j] - mx); dot += t[j] * d[j]; }
  return mx + __logf(se) - dot;
}

__global__ void k_main(const float* __restrict__ enc, const float* __restrict__ dec,
                       const float* __restrict__ tru, WS* __restrict__ ws, int B){
  float mn[10], mx[10];
  #pragma unroll
  for (int c = 0; c < 10; c++){ mn[c] = 3.4e38f; mx[c] = -3.4e38f; }
  float mse_acc = 0.f, ce_acc = 0.f;

  int stride = gridDim.x * blockDim.x;
  for (int r = blockIdx.x * blockDim.x + threadIdx.x; r < B; r += stride){
    // ---- encoded row: per-column min/max ----
    const float2* ep = reinterpret_cast<const float2*>(enc + (size_t)r * 10);
    #pragma unroll
    for (int k = 0; k < 5; k++){
      float2 v = ep[k];
      mn[2*k]   = fminf(mn[2*k],   v.x);  mx[2*k]   = fmaxf(mx[2*k],   v.x);
      mn[2*k+1] = fminf(mn[2*k+1], v.y);  mx[2*k+1] = fmaxf(mx[2*k+1], v.y);
    }
    // ---- decoded + true rows (50 floats each, 8B-aligned since 200r % 8 == 0) ----
    float d[50], t[50];
    const float2* dp = reinterpret_cast<const float2*>(dec + (size_t)r * 50);
    const float2* tp = reinterpret_cast<const float2*>(tru + (size_t)r * 50);
    #pragma unroll
    for (int k = 0; k < 25; k++){ float2 v = dp[k]; d[2*k] = v.x; d[2*k+1] = v.y; }
    #pragma unroll
    for (int k = 0; k < 25; k++){ float2 v = tp[k]; t[2*k] = v.x; t[2*k+1] = v.y; }

    // MSE over cols 0..6
    float m = 0.f;
    #pragma unroll
    for (int j = 0; j < 7; j++){ float e = d[j] - t[j]; m += e * e; }
    mse_acc += m;

    // CE over the 9 blocks (compile-time bounds -> all register-indexed)
    float ce = 0.f;
    ce += ce_block< 7,19>(d, t);
    ce += ce_block<19,21>(d, t);
    ce += ce_block<21,25>(d, t);
    ce += ce_block<25,27>(d, t);
    ce += ce_block<27,29>(d, t);
    ce += ce_block<29,31>(d, t);
    ce += ce_block<31,34>(d, t);
    ce += ce_block<34,38>(d, t);
    ce += ce_block<38,50>(d, t);
    ce_acc += ce;
  }

  // ---- wave reduction (64 lanes) ----
  #pragma unroll
  for (int c = 0; c < 10; c++){
    #pragma unroll
    for (int o = 32; o >= 1; o >>= 1){
      mn[c] = fminf(mn[c], __shfl_xor(mn[c], o));
      mx[c] = fmaxf(mx[c], __shfl_xor(mx[c], o));
    }
  }
  double mseD = (double)mse_acc, ceD = (double)ce_acc;
  #pragma unroll
  for (int o = 32; o >= 1; o >>= 1){
    mseD += __shfl_xor(mseD, o);
    ceD  += __shfl_xor(ceD,  o);
  }
  int lane = threadIdx.x & 63;
  if (lane == 0){
    #pragma unroll
    for (int c = 0; c < 10; c++){
      atomicMin(&ws->minU[c], f2o(mn[c]));
      atomicMax(&ws->maxU[c], f2o(mx[c]));
    }
    atomicAdd(&ws->sum_mse, mseD);
    atomicAdd(&ws->sum_ce,  ceD);
  }
}

__global__ void k_hist(const float* __restrict__ enc, const float* __restrict__ lab,
                       WS* __restrict__ ws, int B){
  __shared__ unsigned int sh[202];
  for (int i = threadIdx.x; i < 202; i += blockDim.x) sh[i] = 0u;
  __syncthreads();

  float mnv[10], wv[10];
  #pragma unroll
  for (int c = 0; c < 10; c++){
    float lo = o2f(ws->minU[c]);
    float hi = o2f(ws->maxU[c]);
    mnv[c] = lo;
    wv[c]  = fmaxf(hi - lo, EPSF);
  }

  int stride = gridDim.x * blockDim.x;
  for (int r = blockIdx.x * blockDim.x + threadIdx.x; r < B; r += stride){
    float g = lab[(size_t)r * 3 + 1];
    int gi = (g == 0.0f) ? 0 : ((g == 1.0f) ? 1 : -1);
    if (gi >= 0){
      atomicAdd(&sh[200 + gi], 1u);
      const float2* ep = reinterpret_cast<const float2*>(enc + (size_t)r * 10);
      #pragma unroll
      for (int k = 0; k < 5; k++){
        float2 v = ep[k];
        {
          int c = 2 * k;
          float bf = floorf((v.x - mnv[c]) / wv[c] * 10.0f);
          int b = (int)bf; b = b < 0 ? 0 : (b > 9 ? 9 : b);
          atomicAdd(&sh[gi * 100 + c * 10 + b], 1u);
        }
        {
          int c = 2 * k + 1;
          float bf = floorf((v.y - mnv[c]) / wv[c] * 10.0f);
          int b = (int)bf; b = b < 0 ? 0 : (b > 9 ? 9 : b);
          atomicAdd(&sh[gi * 100 + c * 10 + b], 1u);
        }
      }
    }
  }
  __syncthreads();
  for (int i = threadIdx.x; i < 202; i += blockDim.x){
    unsigned v = sh[i];
    if (v) atomicAdd(&ws->hist[i], v);
  }
}

__global__ void k_final(WS* __restrict__ ws, float* __restrict__ out, int B){
  float dens = fmaxf((float)ws->hist[200], 1.0f);
  float denm = fmaxf((float)ws->hist[201], 1.0f);
  float kl = 0.f;
  for (int i = threadIdx.x; i < 100; i += 64){
    float p = (float)ws->hist[i]       / dens;
    float q = (float)ws->hist[100 + i] / denm;
    if (p > 0.f) kl += p * logf(p / fmaxf(q, EPSF));
  }
  #pragma unroll
  for (int o = 32; o >= 1; o >>= 1) kl += __shfl_xor(kl, o);

  if (threadIdx.x == 0){
    float mse = (float)(ws->sum_mse / (double)B);
    float ce  = (float)(ws->sum_ce  / (double)B);
    float akld = 0.5f * kl;
    out[0] = 0.5f * (mse + ce) + akld;
    out[1] = mse;
    out[2] = ce;
    out[3] = akld;
  }
}

extern "C" void kernel_launch(void* const* d_in, const int* in_sizes, int n_in,
                              void* d_out, int out_size, void* d_ws, size_t ws_size,
                              hipStream_t stream){
  const float* enc = (const float*)d_in[0];
  const float* dec = (const float*)d_in[1];
  const float* tru = (const float*)d_in[2];
  const float* lab = (const float*)d_in[3];
  int B = in_sizes[1] / 50;

  WS* ws = (WS*)d_ws;
  float* out = (float*)d_out;

  int threads = 256;
  int blocks = (B + threads - 1) / threads;
  if (blocks > 2048) blocks = 2048;

  hipLaunchKernelGGL(k_init, dim3(1), dim3(256), 0, stream, ws);
  hipLaunchKernelGGL(k_main, dim3(blocks), dim3(threads), 0, stream, enc, dec, tru, ws, B);
  hipLaunchKernelGGL(k_hist, dim3(blocks), dim3(threads), 0, stream, enc, lab, ws, B);
  hipLaunchKernelGGL(k_final, dim3(1), dim3(64), 0, stream, ws, out, B);
}

// Round 2
// 1476.194 us; speedup vs baseline: 1.0458x; 1.0458x over previous
//
#include <hip/hip_runtime.h>
#include <math.h>

#define EPSF 1e-10f

struct WS {
  double sum_mse;
  double sum_ce;
  unsigned int minU[10];
  unsigned int maxU[10];
  unsigned int hist[208]; // [0..99] single, [100..199] married, [200]=cnt_single, [201]=cnt_married
};

__device__ __forceinline__ unsigned f2o(float f){
  unsigned u = __float_as_uint(f);
  return (u & 0x80000000u) ? ~u : (u | 0x80000000u);
}
__device__ __forceinline__ float o2f(unsigned u){
  unsigned v = (u & 0x80000000u) ? (u ^ 0x80000000u) : ~u;
  return __uint_as_float(v);
}

__global__ void k_init(WS* ws){
  int t = threadIdx.x;
  if (t == 0){ ws->sum_mse = 0.0; ws->sum_ce = 0.0; }
  if (t < 10){ ws->minU[t] = 0xFFFFFFFFu; ws->maxU[t] = 0u; }
  for (int i = t; i < 208; i += blockDim.x) ws->hist[i] = 0u;
}

// Column-streaming state: online softmax per CE block, everything compile-time.
struct RowState {
  float m, s, dot;
  float mse_acc, ce_acc;
};

__device__ __forceinline__ bool is_start(int j){
  return j==7||j==19||j==21||j==25||j==27||j==29||j==31||j==34||j==38;
}
__device__ __forceinline__ bool is_end(int j){
  return j==18||j==20||j==24||j==26||j==28||j==30||j==33||j==37||j==49;
}

__device__ __forceinline__ void do_col(int j, float d, float t, RowState& st){
  if (j < 7){
    float e = d - t;
    st.mse_acc += e * e;
    return;
  }
  if (is_start(j)){
    st.m = d; st.s = 1.0f; st.dot = t * d;
  } else {
    float mN = fmaxf(st.m, d);
    st.s = st.s * __expf(st.m - mN) + __expf(d - mN);
    st.m = mN;
    st.dot += t * d;
  }
  if (is_end(j)){
    st.ce_acc += st.m + __logf(st.s) - st.dot;
  }
}

__global__ void __launch_bounds__(256, 8)
k_main(const float* __restrict__ enc, const float* __restrict__ dec,
       const float* __restrict__ tru, WS* __restrict__ ws, int B){
  float mn[10], mx[10];
  #pragma unroll
  for (int c = 0; c < 10; c++){ mn[c] = 3.4e38f; mx[c] = -3.4e38f; }
  RowState st;
  st.mse_acc = 0.f; st.ce_acc = 0.f; st.m = 0.f; st.s = 0.f; st.dot = 0.f;

  int stride = gridDim.x * blockDim.x;
  for (int r = blockIdx.x * blockDim.x + threadIdx.x; r < B; r += stride){
    // ---- encoded row: per-column min/max (5x float2) ----
    const float2* ep = reinterpret_cast<const float2*>(enc + (size_t)r * 10);
    #pragma unroll
    for (int k = 0; k < 5; k++){
      float2 v = ep[k];
      mn[2*k]   = fminf(mn[2*k],   v.x);  mx[2*k]   = fmaxf(mx[2*k],   v.x);
      mn[2*k+1] = fminf(mn[2*k+1], v.y);  mx[2*k+1] = fmaxf(mx[2*k+1], v.y);
    }
    // ---- stream decoded/true rows: no per-row arrays, all state in ~8 regs ----
    const float2* dp = reinterpret_cast<const float2*>(dec + (size_t)r * 50);
    const float2* tp = reinterpret_cast<const float2*>(tru + (size_t)r * 50);
    #pragma unroll
    for (int k = 0; k < 25; k++){
      float2 dv = dp[k];
      float2 tv = tp[k];
      do_col(2*k,     dv.x, tv.x, st);
      do_col(2*k + 1, dv.y, tv.y, st);
    }
  }

  // ---- wave reduction (64 lanes) ----
  #pragma unroll
  for (int c = 0; c < 10; c++){
    #pragma unroll
    for (int o = 32; o >= 1; o >>= 1){
      mn[c] = fminf(mn[c], __shfl_xor(mn[c], o));
      mx[c] = fmaxf(mx[c], __shfl_xor(mx[c], o));
    }
  }
  double mseD = (double)st.mse_acc, ceD = (double)st.ce_acc;
  #pragma unroll
  for (int o = 32; o >= 1; o >>= 1){
    mseD += __shfl_xor(mseD, o);
    ceD  += __shfl_xor(ceD,  o);
  }
  int lane = threadIdx.x & 63;
  if (lane == 0){
    #pragma unroll
    for (int c = 0; c < 10; c++){
      atomicMin(&ws->minU[c], f2o(mn[c]));
      atomicMax(&ws->maxU[c], f2o(mx[c]));
    }
    atomicAdd(&ws->sum_mse, mseD);
    atomicAdd(&ws->sum_ce,  ceD);
  }
}

__global__ void k_hist(const float* __restrict__ enc, const float* __restrict__ lab,
                       WS* __restrict__ ws, int B){
  __shared__ unsigned int sh[202];
  for (int i = threadIdx.x; i < 202; i += blockDim.x) sh[i] = 0u;
  __syncthreads();

  float mnv[10], wv[10];
  #pragma unroll
  for (int c = 0; c < 10; c++){
    float lo = o2f(ws->minU[c]);
    float hi = o2f(ws->maxU[c]);
    mnv[c] = lo;
    wv[c]  = fmaxf(hi - lo, EPSF);
  }

  int stride = gridDim.x * blockDim.x;
  for (int r = blockIdx.x * blockDim.x + threadIdx.x; r < B; r += stride){
    float g = lab[(size_t)r * 3 + 1];
    int gi = (g == 0.0f) ? 0 : ((g == 1.0f) ? 1 : -1);
    if (gi >= 0){
      atomicAdd(&sh[200 + gi], 1u);
      const float2* ep = reinterpret_cast<const float2*>(enc + (size_t)r * 10);
      #pragma unroll
      for (int k = 0; k < 5; k++){
        float2 v = ep[k];
        {
          int c = 2 * k;
          float bf = floorf((v.x - mnv[c]) / wv[c] * 10.0f);
          int b = (int)bf; b = b < 0 ? 0 : (b > 9 ? 9 : b);
          atomicAdd(&sh[gi * 100 + c * 10 + b], 1u);
        }
        {
          int c = 2 * k + 1;
          float bf = floorf((v.y - mnv[c]) / wv[c] * 10.0f);
          int b = (int)bf; b = b < 0 ? 0 : (b > 9 ? 9 : b);
          atomicAdd(&sh[gi * 100 + c * 10 + b], 1u);
        }
      }
    }
  }
  __syncthreads();
  for (int i = threadIdx.x; i < 202; i += blockDim.x){
    unsigned v = sh[i];
    if (v) atomicAdd(&ws->hist[i], v);
  }
}

__global__ void k_final(WS* __restrict__ ws, float* __restrict__ out, int B){
  float dens = fmaxf((float)ws->hist[200], 1.0f);
  float denm = fmaxf((float)ws->hist[201], 1.0f);
  float kl = 0.f;
  for (int i = threadIdx.x; i < 100; i += 64){
    float p = (float)ws->hist[i]       / dens;
    float q = (float)ws->hist[100 + i] / denm;
    if (p > 0.f) kl += p * logf(p / fmaxf(q, EPSF));
  }
  #pragma unroll
  for (int o = 32; o >= 1; o >>= 1) kl += __shfl_xor(kl, o);

  if (threadIdx.x == 0){
    float mse = (float)(ws->sum_mse / (double)B);
    float ce  = (float)(ws->sum_ce  / (double)B);
    float akld = 0.5f * kl;
    out[0] = 0.5f * (mse + ce) + akld;
    out[1] = mse;
    out[2] = ce;
    out[3] = akld;
  }
}

extern "C" void kernel_launch(void* const* d_in, const int* in_sizes, int n_in,
                              void* d_out, int out_size, void* d_ws, size_t ws_size,
                              hipStream_t stream){
  const float* enc = (const float*)d_in[0];
  const float* dec = (const float*)d_in[1];
  const float* tru = (const float*)d_in[2];
  const float* lab = (const float*)d_in[3];
  int B = in_sizes[1] / 50;

  WS* ws = (WS*)d_ws;
  float* out = (float*)d_out;

  int threads = 256;
  int blocks = (B + threads - 1) / threads;
  if (blocks > 2048) blocks = 2048;

  hipLaunchKernelGGL(k_init, dim3(1), dim3(256), 0, stream, ws);
  hipLaunchKernelGGL(k_main, dim3(blocks), dim3(threads), 0, stream, enc, dec, tru, ws, B);
  hipLaunchKernelGGL(k_hist, dim3(blocks), dim3(threads), 0, stream, enc, lab, ws, B);
  hipLaunchKernelGGL(k_final, dim3(1), dim3(64), 0, stream, ws, out, B);
}

// Round 3
// 1458.383 us; speedup vs baseline: 1.0586x; 1.0122x over previous
//
#include <hip/hip_runtime.h>
#include <math.h>

#define EPSF 1e-10f

struct WS {
  double sum_mse;
  double sum_ce;
  unsigned int minU[10];
  unsigned int maxU[10];
  unsigned int hist[208]; // [0..99] single, [100..199] married, [200]=cnt_single, [201]=cnt_married
};

__device__ __forceinline__ unsigned f2o(float f){
  unsigned u = __float_as_uint(f);
  return (u & 0x80000000u) ? ~u : (u | 0x80000000u);
}
__device__ __forceinline__ float o2f(unsigned u){
  unsigned v = (u & 0x80000000u) ? (u ^ 0x80000000u) : ~u;
  return __uint_as_float(v);
}

__global__ void k_init(WS* ws){
  int t = threadIdx.x;
  if (t == 0){ ws->sum_mse = 0.0; ws->sum_ce = 0.0; }
  if (t < 10){ ws->minU[t] = 0xFFFFFFFFu; ws->maxU[t] = 0u; }
  for (int i = t; i < 208; i += blockDim.x) ws->hist[i] = 0u;
}

// CE over one softmax block, operands in LDS (compile-time offsets -> registers).
template<int S, int E>
__device__ __forceinline__ float ce_block_lds(const float* __restrict__ d,
                                              const float* __restrict__ t){
  constexpr int N = E - S;
  float dv[N];
  #pragma unroll
  for (int j = 0; j < N; j++) dv[j] = d[S + j];
  float mx = dv[0];
  #pragma unroll
  for (int j = 1; j < N; j++) mx = fmaxf(mx, dv[j]);
  float se = 0.f, dot = 0.f;
  #pragma unroll
  for (int j = 0; j < N; j++){ se += __expf(dv[j] - mx); dot += t[S + j] * dv[j]; }
  return mx + __logf(se) - dot;
}

#define TILE 64

__global__ void k_main(const float* __restrict__ enc, const float* __restrict__ dec,
                       const float* __restrict__ tru, WS* __restrict__ ws, int B){
  __shared__ alignas(16) float ldsD[TILE * 50];
  __shared__ alignas(16) float ldsT[TILE * 50];
  __shared__ alignas(16) float ldsE[TILE * 10];

  const int tid  = threadIdx.x;
  const int wave = tid >> 6;
  const int lane = tid & 63;

  float mn[10], mx[10];
  #pragma unroll
  for (int c = 0; c < 10; c++){ mn[c] = 3.4e38f; mx[c] = -3.4e38f; }
  float mse_acc = 0.f, ce_acc = 0.f;

  const int nTiles = (B + TILE - 1) / TILE;
  for (int tile = blockIdx.x; tile < nTiles; tile += gridDim.x){
    const size_t rowBase = (size_t)tile * TILE;
    const int rowsHere = min(TILE, B - (int)rowBase);
    const int nf  = rowsHere * 50;   // dec/true floats this tile
    const int ne  = rowsHere * 10;   // enc floats this tile

    const float4* dp4 = reinterpret_cast<const float4*>(dec + rowBase * 50);
    const float4* tp4 = reinterpret_cast<const float4*>(tru + rowBase * 50);
    const float4* ep4 = reinterpret_cast<const float4*>(enc + rowBase * 10);
    float4* lD4 = reinterpret_cast<float4*>(ldsD);
    float4* lT4 = reinterpret_cast<float4*>(ldsT);
    float4* lE4 = reinterpret_cast<float4*>(ldsE);

    const int nf4 = nf >> 2, ne4 = ne >> 2;
    for (int i = tid; i < nf4; i += 256){ lD4[i] = dp4[i]; lT4[i] = tp4[i]; }
    for (int i = tid; i < ne4; i += 256){ lE4[i] = ep4[i]; }
    // scalar tails (only possible on a ragged last tile)
    for (int i = (nf4 << 2) + tid; i < nf; i += 256){
      ldsD[i] = dec[rowBase * 50 + i];
      ldsT[i] = tru[rowBase * 50 + i];
    }
    for (int i = (ne4 << 2) + tid; i < ne; i += 256){
      ldsE[i] = enc[rowBase * 10 + i];
    }
    __syncthreads();

    const int row = lane;
    if (row < rowsHere){
      const float* d = ldsD + row * 50;
      const float* t = ldsT + row * 50;
      const float* e = ldsE + row * 10;
      if (wave == 0){
        float m = 0.f;
        #pragma unroll
        for (int j = 0; j < 7; j++){ float df = d[j] - t[j]; m += df * df; }
        mse_acc += m;
        ce_acc += ce_block_lds< 7,19>(d, t);
        #pragma unroll
        for (int c = 0; c < 3; c++){ float v = e[c]; mn[c] = fminf(mn[c], v); mx[c] = fmaxf(mx[c], v); }
      } else if (wave == 1){
        ce_acc += ce_block_lds<19,21>(d, t);
        ce_acc += ce_block_lds<21,25>(d, t);
        ce_acc += ce_block_lds<25,27>(d, t);
        ce_acc += ce_block_lds<27,29>(d, t);
        #pragma unroll
        for (int c = 3; c < 5; c++){ float v = e[c]; mn[c] = fminf(mn[c], v); mx[c] = fmaxf(mx[c], v); }
      } else if (wave == 2){
        ce_acc += ce_block_lds<29,31>(d, t);
        ce_acc += ce_block_lds<31,34>(d, t);
        ce_acc += ce_block_lds<34,38>(d, t);
        #pragma unroll
        for (int c = 5; c < 7; c++){ float v = e[c]; mn[c] = fminf(mn[c], v); mx[c] = fmaxf(mx[c], v); }
      } else {
        ce_acc += ce_block_lds<38,50>(d, t);
        #pragma unroll
        for (int c = 7; c < 10; c++){ float v = e[c]; mn[c] = fminf(mn[c], v); mx[c] = fmaxf(mx[c], v); }
      }
    }
    __syncthreads();
  }

  // ---- wave reduction (64 lanes) ----
  #pragma unroll
  for (int c = 0; c < 10; c++){
    #pragma unroll
    for (int o = 32; o >= 1; o >>= 1){
      mn[c] = fminf(mn[c], __shfl_xor(mn[c], o));
      mx[c] = fmaxf(mx[c], __shfl_xor(mx[c], o));
    }
  }
  double mseD = (double)mse_acc, ceD = (double)ce_acc;
  #pragma unroll
  for (int o = 32; o >= 1; o >>= 1){
    mseD += __shfl_xor(mseD, o);
    ceD  += __shfl_xor(ceD,  o);
  }
  if (lane == 0){
    #pragma unroll
    for (int c = 0; c < 10; c++){
      atomicMin(&ws->minU[c], f2o(mn[c]));
      atomicMax(&ws->maxU[c], f2o(mx[c]));
    }
    atomicAdd(&ws->sum_mse, mseD);
    atomicAdd(&ws->sum_ce,  ceD);
  }
}

__global__ void k_hist(const float* __restrict__ enc, const float* __restrict__ lab,
                       WS* __restrict__ ws, int B){
  __shared__ unsigned int sh[202];
  __shared__ alignas(16) float ldsE[TILE * 10];
  __shared__ alignas(16) float ldsL[TILE * 3];

  const int tid  = threadIdx.x;
  const int wave = tid >> 6;
  const int lane = tid & 63;

  for (int i = tid; i < 202; i += 256) sh[i] = 0u;

  float mnv[10], wv[10];
  #pragma unroll
  for (int c = 0; c < 10; c++){
    float lo = o2f(ws->minU[c]);
    float hi = o2f(ws->maxU[c]);
    mnv[c] = lo;
    wv[c]  = fmaxf(hi - lo, EPSF);
  }
  __syncthreads();

  const int nTiles = (B + TILE - 1) / TILE;
  for (int tile = blockIdx.x; tile < nTiles; tile += gridDim.x){
    const size_t rowBase = (size_t)tile * TILE;
    const int rowsHere = min(TILE, B - (int)rowBase);
    const int ne = rowsHere * 10, nl = rowsHere * 3;

    const float4* ep4 = reinterpret_cast<const float4*>(enc + rowBase * 10);
    const float4* lp4 = reinterpret_cast<const float4*>(lab + rowBase * 3);
    float4* lE4 = reinterpret_cast<float4*>(ldsE);
    float4* lL4 = reinterpret_cast<float4*>(ldsL);
    const int ne4 = ne >> 2, nl4 = nl >> 2;
    for (int i = tid; i < ne4; i += 256) lE4[i] = ep4[i];
    for (int i = tid; i < nl4; i += 256) lL4[i] = lp4[i];
    for (int i = (ne4 << 2) + tid; i < ne; i += 256) ldsE[i] = enc[rowBase * 10 + i];
    for (int i = (nl4 << 2) + tid; i < nl; i += 256) ldsL[i] = lab[rowBase * 3 + i];
    __syncthreads();

    const int row = lane;
    if (row < rowsHere){
      float g = ldsL[row * 3 + 1];
      int gi = (g == 0.0f) ? 0 : ((g == 1.0f) ? 1 : -1);
      if (gi >= 0){
        const float* e = ldsE + row * 10;
        if (wave == 1) atomicAdd(&sh[200 + gi], 1u);
        #define DO_BIN(c) { \
          float bf = floorf((e[(c)] - mnv[(c)]) / wv[(c)] * 10.0f); \
          int b = (int)bf; b = b < 0 ? 0 : (b > 9 ? 9 : b); \
          atomicAdd(&sh[gi * 100 + (c) * 10 + b], 1u); }
        if (wave == 0){ DO_BIN(0) DO_BIN(1) DO_BIN(2) }
        else if (wave == 1){ DO_BIN(3) DO_BIN(4) }
        else if (wave == 2){ DO_BIN(5) DO_BIN(6) }
        else { DO_BIN(7) DO_BIN(8) DO_BIN(9) }
        #undef DO_BIN
      }
    }
    __syncthreads();
  }

  for (int i = tid; i < 202; i += 256){
    unsigned v = sh[i];
    if (v) atomicAdd(&ws->hist[i], v);
  }
}

__global__ void k_final(WS* __restrict__ ws, float* __restrict__ out, int B){
  float dens = fmaxf((float)ws->hist[200], 1.0f);
  float denm = fmaxf((float)ws->hist[201], 1.0f);
  float kl = 0.f;
  for (int i = threadIdx.x; i < 100; i += 64){
    float p = (float)ws->hist[i]       / dens;
    float q = (float)ws->hist[100 + i] / denm;
    if (p > 0.f) kl += p * logf(p / fmaxf(q, EPSF));
  }
  #pragma unroll
  for (int o = 32; o >= 1; o >>= 1) kl += __shfl_xor(kl, o);

  if (threadIdx.x == 0){
    float mse = (float)(ws->sum_mse / (double)B);
    float ce  = (float)(ws->sum_ce  / (double)B);
    float akld = 0.5f * kl;
    out[0] = 0.5f * (mse + ce) + akld;
    out[1] = mse;
    out[2] = ce;
    out[3] = akld;
  }
}

extern "C" void kernel_launch(void* const* d_in, const int* in_sizes, int n_in,
                              void* d_out, int out_size, void* d_ws, size_t ws_size,
                              hipStream_t stream){
  const float* enc = (const float*)d_in[0];
  const float* dec = (const float*)d_in[1];
  const float* tru = (const float*)d_in[2];
  const float* lab = (const float*)d_in[3];
  int B = in_sizes[1] / 50;

  WS* ws = (WS*)d_ws;
  float* out = (float*)d_out;

  const int nTiles = (B + TILE - 1) / TILE;
  int blocks = nTiles < 2048 ? nTiles : 2048;

  hipLaunchKernelGGL(k_init, dim3(1), dim3(256), 0, stream, ws);
  hipLaunchKernelGGL(k_main, dim3(blocks), dim3(256), 0, stream, enc, dec, tru, ws, B);
  hipLaunchKernelGGL(k_hist, dim3(blocks), dim3(256), 0, stream, enc, lab, ws, B);
  hipLaunchKernelGGL(k_final, dim3(1), dim3(64), 0, stream, ws, out, B);
}

// Round 4
// 209.867 us; speedup vs baseline: 7.3561x; 6.9491x over previous
//
#include <hip/hip_runtime.h>
#include <math.h>

#define EPSF 1e-10f
#define TILE 64

struct WS {            // final reduced scalars (written by k_reduce, read by k_hist/k_final)
  double sum_mse, sum_ce;
  float mn[10], mx[10];
};
struct PartM {         // per-block partial from k_main
  double mse, ce;
  float mn[10], mx[10];
};

// CE over one softmax block, operands in LDS (compile-time offsets -> registers).
template<int S, int E>
__device__ __forceinline__ float ce_block_lds(const float* __restrict__ d,
                                              const float* __restrict__ t){
  constexpr int N = E - S;
  float dv[N];
  #pragma unroll
  for (int j = 0; j < N; j++) dv[j] = d[S + j];
  float mx = dv[0];
  #pragma unroll
  for (int j = 1; j < N; j++) mx = fmaxf(mx, dv[j]);
  float se = 0.f, dot = 0.f;
  #pragma unroll
  for (int j = 0; j < N; j++){ se += __expf(dv[j] - mx); dot += t[S + j] * dv[j]; }
  return mx + __logf(se) - dot;
}

__global__ void k_main(const float* __restrict__ enc, const float* __restrict__ dec,
                       const float* __restrict__ tru, PartM* __restrict__ pm,
                       int B, int nbm){
  __shared__ alignas(16) float ldsD[TILE * 50];
  __shared__ alignas(16) float ldsT[TILE * 50];
  __shared__ alignas(16) float ldsE[TILE * 10];
  __shared__ double sMse[4], sCe[4];
  __shared__ float  sMn[4][10], sMx[4][10];

  const int tid  = threadIdx.x;
  const int wave = tid >> 6;
  const int lane = tid & 63;

  float mn[10], mx[10];
  #pragma unroll
  for (int c = 0; c < 10; c++){ mn[c] = 3.4e38f; mx[c] = -3.4e38f; }
  float mse_acc = 0.f, ce_acc = 0.f;

  const int nTiles = (B + TILE - 1) / TILE;
  for (int tile = blockIdx.x; tile < nTiles; tile += nbm){
    const size_t rowBase = (size_t)tile * TILE;
    const int rowsHere = min(TILE, B - (int)rowBase);
    const int nf  = rowsHere * 50;
    const int ne  = rowsHere * 10;

    const float4* dp4 = reinterpret_cast<const float4*>(dec + rowBase * 50);
    const float4* tp4 = reinterpret_cast<const float4*>(tru + rowBase * 50);
    const float4* ep4 = reinterpret_cast<const float4*>(enc + rowBase * 10);
    float4* lD4 = reinterpret_cast<float4*>(ldsD);
    float4* lT4 = reinterpret_cast<float4*>(ldsT);
    float4* lE4 = reinterpret_cast<float4*>(ldsE);

    const int nf4 = nf >> 2, ne4 = ne >> 2;
    for (int i = tid; i < nf4; i += 256){ lD4[i] = dp4[i]; lT4[i] = tp4[i]; }
    for (int i = tid; i < ne4; i += 256){ lE4[i] = ep4[i]; }
    for (int i = (nf4 << 2) + tid; i < nf; i += 256){
      ldsD[i] = dec[rowBase * 50 + i];
      ldsT[i] = tru[rowBase * 50 + i];
    }
    for (int i = (ne4 << 2) + tid; i < ne; i += 256){
      ldsE[i] = enc[rowBase * 10 + i];
    }
    __syncthreads();

    const int row = lane;
    if (row < rowsHere){
      const float* d = ldsD + row * 50;
      const float* t = ldsT + row * 50;
      const float* e = ldsE + row * 10;
      if (wave == 0){
        float m = 0.f;
        #pragma unroll
        for (int j = 0; j < 7; j++){ float df = d[j] - t[j]; m += df * df; }
        mse_acc += m;
        ce_acc += ce_block_lds< 7,19>(d, t);
        #pragma unroll
        for (int c = 0; c < 3; c++){ float v = e[c]; mn[c] = fminf(mn[c], v); mx[c] = fmaxf(mx[c], v); }
      } else if (wave == 1){
        ce_acc += ce_block_lds<19,21>(d, t);
        ce_acc += ce_block_lds<21,25>(d, t);
        ce_acc += ce_block_lds<25,27>(d, t);
        ce_acc += ce_block_lds<27,29>(d, t);
        #pragma unroll
        for (int c = 3; c < 5; c++){ float v = e[c]; mn[c] = fminf(mn[c], v); mx[c] = fmaxf(mx[c], v); }
      } else if (wave == 2){
        ce_acc += ce_block_lds<29,31>(d, t);
        ce_acc += ce_block_lds<31,34>(d, t);
        ce_acc += ce_block_lds<34,38>(d, t);
        #pragma unroll
        for (int c = 5; c < 7; c++){ float v = e[c]; mn[c] = fminf(mn[c], v); mx[c] = fmaxf(mx[c], v); }
      } else {
        ce_acc += ce_block_lds<38,50>(d, t);
        #pragma unroll
        for (int c = 7; c < 10; c++){ float v = e[c]; mn[c] = fminf(mn[c], v); mx[c] = fmaxf(mx[c], v); }
      }
    }
    __syncthreads();
  }

  // ---- wave-level reduction (64 lanes) ----
  #pragma unroll
  for (int c = 0; c < 10; c++){
    #pragma unroll
    for (int o = 32; o >= 1; o >>= 1){
      mn[c] = fminf(mn[c], __shfl_xor(mn[c], o));
      mx[c] = fmaxf(mx[c], __shfl_xor(mx[c], o));
    }
  }
  double mseD = (double)mse_acc, ceD = (double)ce_acc;
  #pragma unroll
  for (int o = 32; o >= 1; o >>= 1){
    mseD += __shfl_xor(mseD, o);
    ceD  += __shfl_xor(ceD,  o);
  }
  // ---- cross-wave via LDS, then ONE plain store per block (no atomics) ----
  if (lane == 0){
    sMse[wave] = mseD; sCe[wave] = ceD;
    #pragma unroll
    for (int c = 0; c < 10; c++){ sMn[wave][c] = mn[c]; sMx[wave][c] = mx[c]; }
  }
  __syncthreads();
  if (tid == 0){
    PartM p;
    p.mse = sMse[0] + sMse[1] + sMse[2] + sMse[3];
    p.ce  = sCe[0]  + sCe[1]  + sCe[2]  + sCe[3];
    #pragma unroll
    for (int c = 0; c < 10; c++){
      p.mn[c] = fminf(fminf(sMn[0][c], sMn[1][c]), fminf(sMn[2][c], sMn[3][c]));
      p.mx[c] = fmaxf(fmaxf(sMx[0][c], sMx[1][c]), fmaxf(sMx[2][c], sMx[3][c]));
    }
    pm[blockIdx.x] = p;
  }
}

__global__ void k_reduce(const PartM* __restrict__ pm, WS* __restrict__ ws, int nbm){
  __shared__ double sMse[4], sCe[4];
  __shared__ float  sMn[4][10], sMx[4][10];
  const int tid  = threadIdx.x;   // 256
  const int wave = tid >> 6;
  const int lane = tid & 63;

  double ms = 0.0, ce = 0.0;
  float mn[10], mx[10];
  #pragma unroll
  for (int c = 0; c < 10; c++){ mn[c] = 3.4e38f; mx[c] = -3.4e38f; }
  for (int i = tid; i < nbm; i += 256){
    ms += pm[i].mse; ce += pm[i].ce;
    #pragma unroll
    for (int c = 0; c < 10; c++){
      mn[c] = fminf(mn[c], pm[i].mn[c]);
      mx[c] = fmaxf(mx[c], pm[i].mx[c]);
    }
  }
  #pragma unroll
  for (int o = 32; o >= 1; o >>= 1){
    ms += __shfl_xor(ms, o);
    ce += __shfl_xor(ce, o);
    #pragma unroll
    for (int c = 0; c < 10; c++){
      mn[c] = fminf(mn[c], __shfl_xor(mn[c], o));
      mx[c] = fmaxf(mx[c], __shfl_xor(mx[c], o));
    }
  }
  if (lane == 0){
    sMse[wave] = ms; sCe[wave] = ce;
    #pragma unroll
    for (int c = 0; c < 10; c++){ sMn[wave][c] = mn[c]; sMx[wave][c] = mx[c]; }
  }
  __syncthreads();
  if (tid == 0){
    ws->sum_mse = sMse[0] + sMse[1] + sMse[2] + sMse[3];
    ws->sum_ce  = sCe[0]  + sCe[1]  + sCe[2]  + sCe[3];
    #pragma unroll
    for (int c = 0; c < 10; c++){
      ws->mn[c] = fminf(fminf(sMn[0][c], sMn[1][c]), fminf(sMn[2][c], sMn[3][c]));
      ws->mx[c] = fmaxf(fmaxf(sMx[0][c], sMx[1][c]), fmaxf(sMx[2][c], sMx[3][c]));
    }
  }
}

__global__ void k_hist(const float* __restrict__ enc, const float* __restrict__ lab,
                       const WS* __restrict__ ws, unsigned* __restrict__ ph,
                       int B, int nbh){
  __shared__ unsigned int sh[202];
  __shared__ alignas(16) float ldsE[TILE * 10];
  __shared__ alignas(16) float ldsL[TILE * 3];

  const int tid  = threadIdx.x;
  const int wave = tid >> 6;
  const int lane = tid & 63;

  for (int i = tid; i < 202; i += 256) sh[i] = 0u;

  float mnv[10], wv[10];
  #pragma unroll
  for (int c = 0; c < 10; c++){
    float lo = ws->mn[c];
    float hi = ws->mx[c];
    mnv[c] = lo;
    wv[c]  = fmaxf(hi - lo, EPSF);
  }
  __syncthreads();

  const int nTiles = (B + TILE - 1) / TILE;
  for (int tile = blockIdx.x; tile < nTiles; tile += nbh){
    const size_t rowBase = (size_t)tile * TILE;
    const int rowsHere = min(TILE, B - (int)rowBase);
    const int ne = rowsHere * 10, nl = rowsHere * 3;

    const float4* ep4 = reinterpret_cast<const float4*>(enc + rowBase * 10);
    const float4* lp4 = reinterpret_cast<const float4*>(lab + rowBase * 3);
    float4* lE4 = reinterpret_cast<float4*>(ldsE);
    float4* lL4 = reinterpret_cast<float4*>(ldsL);
    const int ne4 = ne >> 2, nl4 = nl >> 2;
    for (int i = tid; i < ne4; i += 256) lE4[i] = ep4[i];
    for (int i = tid; i < nl4; i += 256) lL4[i] = lp4[i];
    for (int i = (ne4 << 2) + tid; i < ne; i += 256) ldsE[i] = enc[rowBase * 10 + i];
    for (int i = (nl4 << 2) + tid; i < nl; i += 256) ldsL[i] = lab[rowBase * 3 + i];
    __syncthreads();

    const int row = lane;
    if (row < rowsHere){
      float g = ldsL[row * 3 + 1];
      int gi = (g == 0.0f) ? 0 : ((g == 1.0f) ? 1 : -1);
      if (gi >= 0){
        const float* e = ldsE + row * 10;
        if (wave == 1) atomicAdd(&sh[200 + gi], 1u);
        #define DO_BIN(c) { \
          float bf = floorf((e[(c)] - mnv[(c)]) / wv[(c)] * 10.0f); \
          int b = (int)bf; b = b < 0 ? 0 : (b > 9 ? 9 : b); \
          atomicAdd(&sh[gi * 100 + (c) * 10 + b], 1u); }
        if (wave == 0){ DO_BIN(0) DO_BIN(1) DO_BIN(2) }
        else if (wave == 1){ DO_BIN(3) DO_BIN(4) }
        else if (wave == 2){ DO_BIN(5) DO_BIN(6) }
        else { DO_BIN(7) DO_BIN(8) DO_BIN(9) }
        #undef DO_BIN
      }
    }
    __syncthreads();
  }

  // plain stores of per-block histogram partial (no global atomics)
  unsigned* dst = ph + (size_t)blockIdx.x * 202;
  for (int i = tid; i < 202; i += 256) dst[i] = sh[i];
}

__global__ void k_final(const unsigned* __restrict__ ph, const WS* __restrict__ ws,
                        float* __restrict__ out, int B, int nbh){
  __shared__ float sh[202];
  const int tid = threadIdx.x; // 256
  if (tid < 202){
    unsigned s = 0;
    for (int b = 0; b < nbh; b++) s += ph[(size_t)b * 202 + tid];
    sh[tid] = (float)s;
  }
  __syncthreads();
  if (tid < 64){
    float dens = fmaxf(sh[200], 1.0f);
    float denm = fmaxf(sh[201], 1.0f);
    float kl = 0.f;
    for (int i = tid; i < 100; i += 64){
      float p = sh[i]       / dens;
      float q = sh[100 + i] / denm;
      if (p > 0.f) kl += p * logf(p / fmaxf(q, EPSF));
    }
    #pragma unroll
    for (int o = 32; o >= 1; o >>= 1) kl += __shfl_xor(kl, o);
    if (tid == 0){
      float mse = (float)(ws->sum_mse / (double)B);
      float ce  = (float)(ws->sum_ce  / (double)B);
      float akld = 0.5f * kl;
      out[0] = 0.5f * (mse + ce) + akld;
      out[1] = mse;
      out[2] = ce;
      out[3] = akld;
    }
  }
}

extern "C" void kernel_launch(void* const* d_in, const int* in_sizes, int n_in,
                              void* d_out, int out_size, void* d_ws, size_t ws_size,
                              hipStream_t stream){
  const float* enc = (const float*)d_in[0];
  const float* dec = (const float*)d_in[1];
  const float* tru = (const float*)d_in[2];
  const float* lab = (const float*)d_in[3];
  int B = in_sizes[1] / 50;

  // workspace layout: [WS pad 128][PartM x nbm][uint hist nbh*202]
  int nbm = 1024, nbh = 512;
  while ((size_t)(128 + nbm * (int)sizeof(PartM) + nbh * 202 * 4) > ws_size && nbm > 64){
    nbm >>= 1; nbh >>= 1;
  }
  char* w = (char*)d_ws;
  WS* ws = (WS*)w;
  PartM* pm = (PartM*)(w + 128);
  unsigned* ph = (unsigned*)(w + 128 + (size_t)nbm * sizeof(PartM));
  float* out = (float*)d_out;

  hipLaunchKernelGGL(k_main,   dim3(nbm), dim3(256), 0, stream, enc, dec, tru, pm, B, nbm);
  hipLaunchKernelGGL(k_reduce, dim3(1),   dim3(256), 0, stream, pm, ws, nbm);
  hipLaunchKernelGGL(k_hist,   dim3(nbh), dim3(256), 0, stream, enc, lab, ws, ph, B, nbh);
  hipLaunchKernelGGL(k_final,  dim3(1),   dim3(256), 0, stream, ph, ws, out, B, nbh);
}